// Round 1
// baseline (449.175 us; speedup 1.0000x reference)
//
#include <hip/hip_runtime.h>
#include <math.h>

#define H 1024
#define SEQ 512
#define VOCAB 50257

// workspace offsets (floats)
#define OFF_ALOGIT 0        // 512   attention logits
#define OFF_AW     512      // 512   attention weights
#define OFF_APPLIED 1024    // 1024  attn_applied (atomicAdd -> must be zeroed)
#define OFF_X      2048     // 1024  relu(comb)
#define OFF_GATES  3072     // 4096  lstm gates
#define OFF_H      7168     // 1024  new h
#define OFF_VLOGIT 8192     // 50257 vocab logits
#define OFF_RED    58452    // 2     [max, max+log(sumexp)]

// d_out layout: out[50257] | h[1024] | c[1024] | attn_weights[512]
#define OUT_H   50257
#define OUT_C   (50257 + 1024)
#define OUT_AW  (50257 + 2048)

__device__ __forceinline__ float wave_sum(float v) {
    for (int off = 32; off; off >>= 1) v += __shfl_down(v, off, 64);
    return v;
}
__device__ __forceinline__ float wave_max(float v) {
    for (int off = 32; off; off >>= 1) v = fmaxf(v, __shfl_down(v, off, 64));
    return v;
}

// ---- K1: attention logits: logit[s] = dot(concat(emb[idx], h0), attn_W[s]) + attn_b[s]
__global__ void k_attn_logits(const float* __restrict__ emb, const int* __restrict__ idx,
                              const float* __restrict__ h0, const float* __restrict__ attn_W,
                              const float* __restrict__ attn_b, float* __restrict__ ws) {
    __shared__ float red[4];
    const int s = blockIdx.x, t = threadIdx.x;
    const float* erow = emb + (long)idx[0] * H;
    const float* wrow = attn_W + (long)s * (2 * H);
    float acc = 0.f;
    for (int k = t; k < 2 * H; k += 256) {
        float a = (k < H) ? erow[k] : h0[k - H];
        acc += a * wrow[k];
    }
    acc = wave_sum(acc);
    if ((t & 63) == 0) red[t >> 6] = acc;
    __syncthreads();
    if (t == 0) ws[OFF_ALOGIT + s] = red[0] + red[1] + red[2] + red[3] + attn_b[s];
}

// ---- K2: softmax over 512 logits -> ws[OFF_AW] and d_out attn_weights
__global__ void k_softmax(float* __restrict__ ws, float* __restrict__ out_aw) {
    __shared__ float red[8];
    __shared__ float bc;
    const int t = threadIdx.x;            // 512 threads
    const int lane = t & 63, wid = t >> 6;
    float v = ws[OFF_ALOGIT + t];
    float m = wave_max(v);
    if (lane == 0) red[wid] = m;
    __syncthreads();
    if (t == 0) {
        float r = red[0];
        for (int w = 1; w < 8; ++w) r = fmaxf(r, red[w]);
        bc = r;
    }
    __syncthreads();
    float e = expf(v - bc);
    __syncthreads();
    float s = wave_sum(e);
    if (lane == 0) red[wid] = s;
    __syncthreads();
    if (t == 0) {
        float r = 0.f;
        for (int w = 0; w < 8; ++w) r += red[w];
        bc = r;
    }
    __syncthreads();
    float w = e / bc;
    ws[OFF_AW + t] = w;
    out_aw[t] = w;
}

// ---- K3: attn_applied[h] += sum_{s in chunk} aw[s]*enc[s][h]  (split-K, atomics)
__global__ void k_attn_applied(const float* __restrict__ enc, float* __restrict__ ws) {
    const int hb = blockIdx.x & 3, sc = blockIdx.x >> 2;  // grid 64
    const int h = hb * 256 + threadIdx.x;
    const int s0 = sc * 32;
    float acc = 0.f;
    for (int s = s0; s < s0 + 32; ++s)
        acc += ws[OFF_AW + s] * enc[s * H + h];
    atomicAdd(&ws[OFF_APPLIED + h], acc);
}

// ---- K4: x[h] = relu(dot(concat(emb[idx], applied), comb_W[h]) + comb_b[h])
__global__ void k_comb(const float* __restrict__ emb, const int* __restrict__ idx,
                       const float* __restrict__ comb_W, const float* __restrict__ comb_b,
                       float* __restrict__ ws) {
    __shared__ float red[4];
    const int h = blockIdx.x, t = threadIdx.x;
    const float* erow = emb + (long)idx[0] * H;
    const float* wrow = comb_W + (long)h * (2 * H);
    float acc = 0.f;
    for (int k = t; k < 2 * H; k += 256) {
        float a = (k < H) ? erow[k] : ws[OFF_APPLIED + k - H];
        acc += a * wrow[k];
    }
    acc = wave_sum(acc);
    if ((t & 63) == 0) red[t >> 6] = acc;
    __syncthreads();
    if (t == 0) ws[OFF_X + h] = fmaxf(red[0] + red[1] + red[2] + red[3] + comb_b[h], 0.f);
}

// ---- K5: gates[j] = dot(x, w_ih[j]) + dot(h0, w_hh[j]) + b_ih[j] + b_hh[j]
__global__ void k_gates(const float* __restrict__ w_ih, const float* __restrict__ w_hh,
                        const float* __restrict__ b_ih, const float* __restrict__ b_hh,
                        const float* __restrict__ h0, float* __restrict__ ws) {
    __shared__ float red[4];
    const int j = blockIdx.x, t = threadIdx.x;
    const float* wi = w_ih + (long)j * H;
    const float* wh = w_hh + (long)j * H;
    float acc = 0.f;
    for (int k = t; k < H; k += 256)
        acc += ws[OFF_X + k] * wi[k] + h0[k] * wh[k];
    acc = wave_sum(acc);
    if ((t & 63) == 0) red[t >> 6] = acc;
    __syncthreads();
    if (t == 0) ws[OFF_GATES + j] = red[0] + red[1] + red[2] + red[3] + b_ih[j] + b_hh[j];
}

// ---- K6: LSTM elementwise; writes h,c to d_out and h to ws
__global__ void k_lstm(const float* __restrict__ c0, float* __restrict__ ws,
                       float* __restrict__ dout) {
    const int t = blockIdx.x * 256 + threadIdx.x;  // grid 4
    float gi = ws[OFF_GATES + t];
    float gf = ws[OFF_GATES + H + t];
    float gg = ws[OFF_GATES + 2 * H + t];
    float go = ws[OFF_GATES + 3 * H + t];
    float i = 1.f / (1.f + expf(-gi));
    float f = 1.f / (1.f + expf(-gf));
    float g = tanhf(gg);
    float o = 1.f / (1.f + expf(-go));
    float c = f * c0[t] + i * g;
    float h = o * tanhf(c);
    dout[OUT_H + t] = h;
    dout[OUT_C + t] = c;
    ws[OFF_H + t] = h;
}

// ---- K7: vocab logits, wave-per-row, float4 loads
__global__ void k_vocab(const float* __restrict__ out_W, const float* __restrict__ out_b,
                        float* __restrict__ ws) {
    __shared__ __align__(16) float hs[H];
    const int t = threadIdx.x;
    for (int k = t; k < H; k += 256) hs[k] = ws[OFF_H + k];
    __syncthreads();
    const int wid = t >> 6, lane = t & 63;
    const int r = blockIdx.x * 4 + wid;
    if (r < VOCAB) {
        const float* wrow = out_W + (long)r * H;
        float acc = 0.f;
        #pragma unroll
        for (int it = 0; it < 4; ++it) {
            int k = it * 256 + lane * 4;
            float4 w = *(const float4*)(wrow + k);
            float4 hv = *(const float4*)(hs + k);
            acc += w.x * hv.x + w.y * hv.y + w.z * hv.z + w.w * hv.w;
        }
        acc = wave_sum(acc);
        if (lane == 0) ws[OFF_VLOGIT + r] = acc + out_b[r];
    }
}

// ---- K8: max + log-sum-exp over 50257 (single block, 1024 threads)
__global__ void k_lse(float* __restrict__ ws) {
    __shared__ float red[16];
    __shared__ float bc;
    const int t = threadIdx.x, lane = t & 63, wid = t >> 6;
    float m = -INFINITY;
    for (int v = t; v < VOCAB; v += 1024) m = fmaxf(m, ws[OFF_VLOGIT + v]);
    m = wave_max(m);
    if (lane == 0) red[wid] = m;
    __syncthreads();
    if (t == 0) {
        float r = red[0];
        for (int w = 1; w < 16; ++w) r = fmaxf(r, red[w]);
        bc = r;
    }
    __syncthreads();
    m = bc;
    float s = 0.f;
    for (int v = t; v < VOCAB; v += 1024) s += expf(ws[OFF_VLOGIT + v] - m);
    __syncthreads();
    s = wave_sum(s);
    if (lane == 0) red[wid] = s;
    __syncthreads();
    if (t == 0) {
        float r = 0.f;
        for (int w = 0; w < 16; ++w) r += red[w];
        ws[OFF_RED] = m;
        ws[OFF_RED + 1] = m + logf(r);
    }
}

// ---- K9: final log-softmax write
__global__ void k_write(const float* __restrict__ ws, float* __restrict__ dout) {
    const int v = blockIdx.x * 256 + threadIdx.x;
    if (v < VOCAB) dout[v] = ws[OFF_VLOGIT + v] - ws[OFF_RED + 1];
}

extern "C" void kernel_launch(void* const* d_in, const int* in_sizes, int n_in,
                              void* d_out, int out_size, void* d_ws, size_t ws_size,
                              hipStream_t stream) {
    const int*   idx    = (const int*)d_in[0];
    const float* h0     = (const float*)d_in[1];
    const float* c0     = (const float*)d_in[2];
    const float* enc    = (const float*)d_in[3];
    const float* emb    = (const float*)d_in[4];
    const float* attn_W = (const float*)d_in[5];
    const float* attn_b = (const float*)d_in[6];
    const float* comb_W = (const float*)d_in[7];
    const float* comb_b = (const float*)d_in[8];
    const float* w_ih   = (const float*)d_in[9];
    const float* w_hh   = (const float*)d_in[10];
    const float* b_ih   = (const float*)d_in[11];
    const float* b_hh   = (const float*)d_in[12];
    const float* out_W  = (const float*)d_in[13];
    const float* out_b  = (const float*)d_in[14];
    float* ws  = (float*)d_ws;
    float* out = (float*)d_out;

    // zero the atomic-accumulated attn_applied region (ws is poisoned 0xAA)
    hipMemsetAsync(ws + OFF_APPLIED, 0, H * sizeof(float), stream);

    k_attn_logits<<<SEQ, 256, 0, stream>>>(emb, idx, h0, attn_W, attn_b, ws);
    k_softmax<<<1, SEQ, 0, stream>>>(ws, out + OUT_AW);
    k_attn_applied<<<64, 256, 0, stream>>>(enc, ws);
    k_comb<<<H, 256, 0, stream>>>(emb, idx, comb_W, comb_b, ws);
    k_gates<<<4 * H, 256, 0, stream>>>(w_ih, w_hh, b_ih, b_hh, h0, ws);
    k_lstm<<<4, 256, 0, stream>>>(c0, ws, out);
    k_vocab<<<(VOCAB + 3) / 4, 256, 0, stream>>>(out_W, out_b, ws);
    k_lse<<<1, 1024, 0, stream>>>(ws);
    k_write<<<(VOCAB + 255) / 256, 256, 0, stream>>>(ws, out);
}